// Round 5
// baseline (657.265 us; speedup 1.0000x reference)
//
#include <hip/hip_runtime.h>
#include <stdint.h>
#include <math.h>

#define NN 8192
#define DIM 64
#define KSEL 32
#define BK 16
#define TILE 128

// ---- XLA/Eigen f32 tanh rational approximation (bit-exact emulation) ----
// clamp to +-7.90531110763549805; |x| < 0.0004 -> x; else x*P(x^2)/Q(x^2),
// all products/sums fused exactly as Eigen's pmadd chain.
__device__ __forceinline__ float tanh_xla(float x) {
    const float kClamp = 7.90531110763549805f;
    float xc = fminf(fmaxf(x, -kClamp), kClamp);
    float x2 = xc * xc;
    float p = -2.76076847742355e-16f;
    p = fmaf(x2, p, 2.00018790482477e-13f);
    p = fmaf(x2, p, -8.60467152213735e-11f);
    p = fmaf(x2, p, 5.12229709037114e-08f);
    p = fmaf(x2, p, 1.48572235717979e-05f);
    p = fmaf(x2, p, 6.37261928875436e-04f);
    p = fmaf(x2, p, 4.89352455891786e-03f);
    p = xc * p;
    float q = 1.19825839466702e-06f;
    q = fmaf(x2, q, 1.18534705686654e-04f);
    q = fmaf(x2, q, 2.26843463243900e-03f);
    q = fmaf(x2, q, 4.89352518554385e-03f);
    float r = p / q;
    return (fabsf(x) < 0.0004f) ? x : r;
}
// positive-input variant (ax >= 0), same bits as tanh_xla(ax)
__device__ __forceinline__ float tanh_xla_pos(float ax) {
    const float kClamp = 7.90531110763549805f;
    float xc = fminf(ax, kClamp);
    float x2 = xc * xc;
    float p = -2.76076847742355e-16f;
    p = fmaf(x2, p, 2.00018790482477e-13f);
    p = fmaf(x2, p, -8.60467152213735e-11f);
    p = fmaf(x2, p, 5.12229709037114e-08f);
    p = fmaf(x2, p, 1.48572235717979e-05f);
    p = fmaf(x2, p, 6.37261928875436e-04f);
    p = fmaf(x2, p, 4.89352455891786e-03f);
    p = xc * p;
    float q = 1.19825839466702e-06f;
    q = fmaf(x2, q, 1.18534705686654e-04f);
    q = fmaf(x2, q, 2.26843463243900e-03f);
    q = fmaf(x2, q, 4.89352518554385e-03f);
    float r = p / q;
    return (ax < 0.0004f) ? ax : r;
}

// ---- kernel 1: V = tanh_xla(3*(E[idx] @ W.T + b)) in f32, XLA order ----
// dot: single fmaf chain ascending k, bias added AFTER, then *3.0f.
__global__ __launch_bounds__(256) void k_embed(
    const int* __restrict__ gidx,
    const float* __restrict__ E1, const float* __restrict__ E2,
    const float* __restrict__ W1, const float* __restrict__ b1,
    const float* __restrict__ W2, const float* __restrict__ b2,
    float* __restrict__ V1, float* __restrict__ V2)
{
    __shared__ float W1s[DIM][DIM + 1];
    __shared__ float W2s[DIM][DIM + 1];
    __shared__ float E1s[4][DIM];
    __shared__ float E2s[4][DIM];
    const int t = threadIdx.x;
    for (int i = t; i < DIM * DIM; i += 256) {
        W1s[i >> 6][i & 63] = W1[i];
        W2s[i >> 6][i & 63] = W2[i];
    }
    const int rbase = blockIdx.x * 4;
    for (int i = t; i < 4 * DIM; i += 256) {
        const int r = i >> 6, k = i & 63;
        const int g = gidx[rbase + r];
        E1s[r][k] = E1[(size_t)g * DIM + k];
        E2s[r][k] = E2[(size_t)g * DIM + k];
    }
    __syncthreads();
    const int o = t & 63, rs = t >> 6;
    float m1 = 0.0f, m2 = 0.0f;
    #pragma unroll
    for (int k = 0; k < DIM; ++k) {
        m1 = fmaf(E1s[rs][k], W1s[o][k], m1);
        m2 = fmaf(E2s[rs][k], W2s[o][k], m2);
    }
    V1[(size_t)(rbase + rs) * DIM + o] = tanh_xla(3.0f * (m1 + b1[o]));
    V2[(size_t)(rbase + rs) * DIM + o] = tanh_xla(3.0f * (m2 + b2[o]));
}

// ---- kernel 2: A = relu(tanh_xla(3*(M1 - M2))), M1/M2 separate f32 fmaf ----
// ---- chains ascending k (XLA/BLAS emulation); antisymmetric mirror.     ----
__global__ __launch_bounds__(512) void k_score(
    const float* __restrict__ V1, const float* __restrict__ V2,
    float* __restrict__ out)
{
    const int bi = blockIdx.y, bj = blockIdx.x;
    if (bj < bi) return;                       // lower tri filled by mirror
    __shared__ float sV1I[BK][TILE + 1];
    __shared__ float sV2I[BK][TILE + 1];
    __shared__ float sV1J[BK][TILE + 1];
    __shared__ float sV2J[BK][TILE + 1];

    const int tx = threadIdx.x;                // 0..15 -> 8 cols each
    const int ty = threadIdx.y;                // 0..31 -> 4 rows each
    const int t = ty * 16 + tx;
    const int Ibase = bi * TILE, Jbase = bj * TILE;

    float acc1[4][8], acc2[4][8];
    #pragma unroll
    for (int i = 0; i < 4; ++i)
        #pragma unroll
        for (int j = 0; j < 8; ++j) { acc1[i][j] = 0.0f; acc2[i][j] = 0.0f; }

    for (int ck = 0; ck < DIM; ck += BK) {     // ck ascending -> global k order
        __syncthreads();
        {   // stage [BK][TILE] chunks transposed; 512 thr, 1 float4 per array
            const int r  = t >> 2;             // 0..127
            const int k4 = (t & 3) * 4;        // 0,4,8,12
            float4 f;
            f = *(const float4*)&V1[(size_t)(Ibase + r) * DIM + ck + k4];
            sV1I[k4+0][r]=f.x; sV1I[k4+1][r]=f.y; sV1I[k4+2][r]=f.z; sV1I[k4+3][r]=f.w;
            f = *(const float4*)&V2[(size_t)(Ibase + r) * DIM + ck + k4];
            sV2I[k4+0][r]=f.x; sV2I[k4+1][r]=f.y; sV2I[k4+2][r]=f.z; sV2I[k4+3][r]=f.w;
            f = *(const float4*)&V1[(size_t)(Jbase + r) * DIM + ck + k4];
            sV1J[k4+0][r]=f.x; sV1J[k4+1][r]=f.y; sV1J[k4+2][r]=f.z; sV1J[k4+3][r]=f.w;
            f = *(const float4*)&V2[(size_t)(Jbase + r) * DIM + ck + k4];
            sV2J[k4+0][r]=f.x; sV2J[k4+1][r]=f.y; sV2J[k4+2][r]=f.z; sV2J[k4+3][r]=f.w;
        }
        __syncthreads();
        for (int k = 0; k < BK; ++k) {         // k ascending (bit-order matters)
            float a1v[4], a2v[4], c1v[8], c2v[8];
            #pragma unroll
            for (int i = 0; i < 4; ++i) {
                a1v[i] = sV1I[k][ty * 4 + i];
                a2v[i] = sV2I[k][ty * 4 + i];
            }
            #pragma unroll
            for (int j = 0; j < 8; ++j) {
                c1v[j] = sV1J[k][tx * 8 + j];
                c2v[j] = sV2J[k][tx * 8 + j];
            }
            #pragma unroll
            for (int i = 0; i < 4; ++i)
                #pragma unroll
                for (int j = 0; j < 8; ++j) {
                    acc1[i][j] = fmaf(a1v[i], c2v[j], acc1[i][j]);  // M1: v1_i.v2_j
                    acc2[i][j] = fmaf(a2v[i], c1v[j], acc2[i][j]);  // M2: v2_i.v1_j
                }
        }
    }
    float wn[4][8], wm[4][8];
    #pragma unroll
    for (int i = 0; i < 4; ++i)
        #pragma unroll
        for (int j = 0; j < 8; ++j) {
            const float aa = acc1[i][j] - acc2[i][j];   // M1 - M2 (one f32 sub)
            const float ax = 3.0f * fabsf(aa);          // |3*aa| bitwise
            const float tt = tanh_xla_pos(ax);
            wn[i][j] = (aa > 0.0f) ? tt : 0.0f;         // relu(tanh(3a))
            wm[i][j] = (aa < 0.0f) ? tt : 0.0f;         // relu(tanh(-3a))
        }
    #pragma unroll
    for (int i = 0; i < 4; ++i) {
        const int gi = Ibase + ty * 4 + i;
        float4* p = (float4*)&out[(size_t)gi * NN + Jbase + tx * 8];
        p[0] = make_float4(wn[i][0], wn[i][1], wn[i][2], wn[i][3]);
        p[1] = make_float4(wn[i][4], wn[i][5], wn[i][6], wn[i][7]);
    }
    if (bi != bj) {   // mirrored tile (rows J, cols I)
        #pragma unroll
        for (int j = 0; j < 8; ++j) {
            const int gj = Jbase + tx * 8 + j;
            *(float4*)&out[(size_t)gj * NN + Ibase + ty * 4] =
                make_float4(wm[0][j], wm[1][j], wm[2][j], wm[3][j]);
        }
    }
}

// ---- kernel 3: exact stable top-32 per row, 44-bit radix select ----
// key = (A_bits << 13) | (8191 - col): value desc then index asc (ties ->
// lowest index) = jax.lax.top_k semantics on f32 A. Keys unique.
__global__ __launch_bounds__(256) void k_topk(float* __restrict__ out)
{
    __shared__ uint32_t hist[4][2048];
    __shared__ uint32_t waveTot[4];
    __shared__ uint32_t bc_bin, bc_ca, bc_flag;

    const int row = blockIdx.x;
    const int t = threadIdx.x;
    const int wid = t >> 6, lane = t & 63;
    float* rp = out + (size_t)row * NN;

    float v[32];
    #pragma unroll
    for (int s = 0; s < 8; ++s) {
        const float4 f = *(const float4*)&rp[(s * 256 + t) * 4];
        v[s*4+0] = f.x; v[s*4+1] = f.y; v[s*4+2] = f.z; v[s*4+3] = f.w;
    }
    if (t == 0) bc_flag = 0;

    uint64_t prefix = 0, thr = 0;
    int need = KSEL;
    bool done = false;   // block-uniform

    for (int pass = 0; pass < 4; ++pass) {
        const int shift = 33 - 11 * pass;
        for (int i = t; i < 4 * 2048; i += 256) ((uint32_t*)hist)[i] = 0;
        __syncthreads();
        if (!done) {
            #pragma unroll
            for (int s = 0; s < 8; ++s) {
                #pragma unroll
                for (int e = 0; e < 4; ++e) {
                    const uint32_t vb = __float_as_uint(v[s*4+e]);
                    if (vb == 0u) continue;
                    const int gi = s * 1024 + t * 4 + e;
                    const uint64_t key = ((uint64_t)vb << 13) | (uint32_t)(8191 - gi);
                    if ((key >> (shift + 11)) == prefix)
                        atomicAdd(&hist[wid][(uint32_t)((key >> shift) & 2047u)], 1u);
                }
            }
        }
        __syncthreads();
        uint32_t m[8]; uint32_t tot = 0;
        if (!done) {
            #pragma unroll
            for (int i = 0; i < 8; ++i) {
                const int b = t * 8 + i;
                m[i] = hist[0][b] + hist[1][b] + hist[2][b] + hist[3][b];
                tot += m[i];
            }
        }
        uint32_t ssum = tot;   // inclusive suffix-sum within wave
        #pragma unroll
        for (int d = 1; d < 64; d <<= 1) {
            const uint32_t o = __shfl_down(ssum, d, 64);
            if (lane + d < 64) ssum += o;
        }
        if (lane == 0) waveTot[wid] = ssum;
        __syncthreads();
        if (!done) {
            uint32_t above = 0;
            for (int w2 = wid + 1; w2 < 4; ++w2) above += waveTot[w2];
            if (pass == 0) {
                const uint32_t totalAll = waveTot[0] + waveTot[1] + waveTot[2] + waveTot[3];
                if (totalAll < (uint32_t)need && t == 0) bc_flag = 1;  // <32 positives
            }
            uint32_t c = (ssum - tot) + above;
            #pragma unroll
            for (int i = 7; i >= 0; --i) {
                if (c < (uint32_t)need && (uint32_t)need <= c + m[i]) {
                    bc_bin = (uint32_t)(t * 8 + i);
                    bc_ca  = c;
                }
                c += m[i];
            }
        }
        __syncthreads();
        if (!done) {
            if (bc_flag) { thr = 1; done = true; }          // keep all positives
            else {
                prefix = (prefix << 11) | (uint64_t)bc_bin;
                need  -= (int)bc_ca;
                if (pass == 3) { thr = prefix; done = true; }
            }
        }
        __syncthreads();
    }

    #pragma unroll
    for (int s = 0; s < 8; ++s) {
        float w[4];
        #pragma unroll
        for (int e = 0; e < 4; ++e) {
            const float a = v[s*4+e];
            const uint32_t vb = __float_as_uint(a);
            const int gi = s * 1024 + t * 4 + e;
            const uint64_t key = ((uint64_t)vb << 13) | (uint32_t)(8191 - gi);
            w[e] = (vb != 0u && key >= thr) ? a : 0.f;
        }
        *(float4*)&rp[(s * 256 + t) * 4] = make_float4(w[0], w[1], w[2], w[3]);
    }
}

extern "C" void kernel_launch(void* const* d_in, const int* in_sizes, int n_in,
                              void* d_out, int out_size, void* d_ws, size_t ws_size,
                              hipStream_t stream)
{
    const int*   idx = (const int*)  d_in[0];
    const float* E1  = (const float*)d_in[1];
    const float* E2  = (const float*)d_in[2];
    const float* W1  = (const float*)d_in[3];
    const float* b1  = (const float*)d_in[4];
    const float* W2  = (const float*)d_in[5];
    const float* b2  = (const float*)d_in[6];
    float* out = (float*)d_out;
    float* V1 = (float*)d_ws;                 // 2 MB
    float* V2 = V1 + (size_t)NN * DIM;        // 2 MB

    k_embed<<<NN / 4, 256, 0, stream>>>(idx, E1, E2, W1, b1, W2, b2, V1, V2);
    k_score<<<dim3(NN / TILE, NN / TILE), dim3(16, 32), 0, stream>>>(V1, V2, out);
    k_topk<<<NN, 256, 0, stream>>>(out);
}

// Round 6
// 327.180 us; speedup vs baseline: 2.0089x; 2.0089x over previous
//
#include <hip/hip_runtime.h>
#include <stdint.h>
#include <math.h>

#define NN 8192
#define DIM 64
#define KSEL 32
#define BK2 32
#define TILE 128

// ---- XLA/Eigen f32 tanh rational approximation (bit-exact emulation) ----
__device__ __forceinline__ float tanh_xla(float x) {
    const float kClamp = 7.90531110763549805f;
    float xc = fminf(fmaxf(x, -kClamp), kClamp);
    float x2 = xc * xc;
    float p = -2.76076847742355e-16f;
    p = fmaf(x2, p, 2.00018790482477e-13f);
    p = fmaf(x2, p, -8.60467152213735e-11f);
    p = fmaf(x2, p, 5.12229709037114e-08f);
    p = fmaf(x2, p, 1.48572235717979e-05f);
    p = fmaf(x2, p, 6.37261928875436e-04f);
    p = fmaf(x2, p, 4.89352455891786e-03f);
    p = xc * p;
    float q = 1.19825839466702e-06f;
    q = fmaf(x2, q, 1.18534705686654e-04f);
    q = fmaf(x2, q, 2.26843463243900e-03f);
    q = fmaf(x2, q, 4.89352518554385e-03f);
    float r = p / q;
    return (fabsf(x) < 0.0004f) ? x : r;
}
// positive-input variant (ax >= 0), same bits as tanh_xla(ax)
__device__ __forceinline__ float tanh_xla_pos(float ax) {
    const float kClamp = 7.90531110763549805f;
    float xc = fminf(ax, kClamp);
    float x2 = xc * xc;
    float p = -2.76076847742355e-16f;
    p = fmaf(x2, p, 2.00018790482477e-13f);
    p = fmaf(x2, p, -8.60467152213735e-11f);
    p = fmaf(x2, p, 5.12229709037114e-08f);
    p = fmaf(x2, p, 1.48572235717979e-05f);
    p = fmaf(x2, p, 6.37261928875436e-04f);
    p = fmaf(x2, p, 4.89352455891786e-03f);
    p = xc * p;
    float q = 1.19825839466702e-06f;
    q = fmaf(x2, q, 1.18534705686654e-04f);
    q = fmaf(x2, q, 2.26843463243900e-03f);
    q = fmaf(x2, q, 4.89352518554385e-03f);
    float r = p / q;
    return (ax < 0.0004f) ? ax : r;
}

// ---- kernel 1: V = tanh_xla(3*(E[idx] @ W.T + b)) in f32, XLA order ----
__global__ __launch_bounds__(256) void k_embed(
    const int* __restrict__ gidx,
    const float* __restrict__ E1, const float* __restrict__ E2,
    const float* __restrict__ W1, const float* __restrict__ b1,
    const float* __restrict__ W2, const float* __restrict__ b2,
    float* __restrict__ V1, float* __restrict__ V2)
{
    __shared__ float W1s[DIM][DIM + 1];
    __shared__ float W2s[DIM][DIM + 1];
    __shared__ float E1s[4][DIM];
    __shared__ float E2s[4][DIM];
    const int t = threadIdx.x;
    for (int i = t; i < DIM * DIM; i += 256) {
        W1s[i >> 6][i & 63] = W1[i];
        W2s[i >> 6][i & 63] = W2[i];
    }
    const int rbase = blockIdx.x * 4;
    for (int i = t; i < 4 * DIM; i += 256) {
        const int r = i >> 6, k = i & 63;
        const int g = gidx[rbase + r];
        E1s[r][k] = E1[(size_t)g * DIM + k];
        E2s[r][k] = E2[(size_t)g * DIM + k];
    }
    __syncthreads();
    const int o = t & 63, rs = t >> 6;
    float m1 = 0.0f, m2 = 0.0f;
    #pragma unroll
    for (int k = 0; k < DIM; ++k) {
        m1 = fmaf(E1s[rs][k], W1s[o][k], m1);
        m2 = fmaf(E2s[rs][k], W2s[o][k], m2);
    }
    V1[(size_t)(rbase + rs) * DIM + o] = tanh_xla(3.0f * (m1 + b1[o]));
    V2[(size_t)(rbase + rs) * DIM + o] = tanh_xla(3.0f * (m2 + b2[o]));
}

// ---- kernel 2: A = relu(tanh_xla(3*(M1 - M2))), bit-exact XLA chains. ----
// 256 thr, 8x8/thread, k-major LDS [BK2][TILE] (no pad): all fragment
// reads are aligned ds_read_b128, conflict-free; staging writes 2-way.
__global__ __launch_bounds__(256, 2) void k_score(
    const float* __restrict__ V1, const float* __restrict__ V2,
    float* __restrict__ out)
{
    const int bi = blockIdx.y, bj = blockIdx.x;
    if (bj < bi) return;                       // lower tri filled by mirror
    __shared__ float sA1[BK2][TILE];           // V1 rows I, k-major
    __shared__ float sA2[BK2][TILE];           // V2 rows I
    __shared__ float sB1[BK2][TILE];           // V1 rows J
    __shared__ float sB2[BK2][TILE];           // V2 rows J

    const int t = threadIdx.x;
    const int tx = t & 15;                     // 8 cols each
    const int ty = t >> 4;                     // 8 rows each
    const int Ibase = bi * TILE, Jbase = bj * TILE;

    float acc1[8][8], acc2[8][8];
    #pragma unroll
    for (int i = 0; i < 8; ++i)
        #pragma unroll
        for (int j = 0; j < 8; ++j) { acc1[i][j] = 0.0f; acc2[i][j] = 0.0f; }

    for (int ck = 0; ck < DIM; ck += BK2) {    // ascending k chunks
        __syncthreads();
        #pragma unroll
        for (int it = 0; it < 4; ++it) {       // stage transposed, r = lane-fast
            const int idx = it * 256 + t;      // 0..1023
            const int r   = idx & 127;
            const int c4  = idx >> 7;          // 0..7
            float4 f;
            f = *(const float4*)&V1[(size_t)(Ibase + r) * DIM + ck + c4 * 4];
            sA1[c4*4+0][r]=f.x; sA1[c4*4+1][r]=f.y; sA1[c4*4+2][r]=f.z; sA1[c4*4+3][r]=f.w;
            f = *(const float4*)&V2[(size_t)(Ibase + r) * DIM + ck + c4 * 4];
            sA2[c4*4+0][r]=f.x; sA2[c4*4+1][r]=f.y; sA2[c4*4+2][r]=f.z; sA2[c4*4+3][r]=f.w;
            f = *(const float4*)&V1[(size_t)(Jbase + r) * DIM + ck + c4 * 4];
            sB1[c4*4+0][r]=f.x; sB1[c4*4+1][r]=f.y; sB1[c4*4+2][r]=f.z; sB1[c4*4+3][r]=f.w;
            f = *(const float4*)&V2[(size_t)(Jbase + r) * DIM + ck + c4 * 4];
            sB2[c4*4+0][r]=f.x; sB2[c4*4+1][r]=f.y; sB2[c4*4+2][r]=f.z; sB2[c4*4+3][r]=f.w;
        }
        __syncthreads();
        #pragma unroll 2
        for (int k = 0; k < BK2; ++k) {        // strictly ascending k
            float a1[8], a2[8], c1[8], c2[8];
            *(float4*)&a1[0] = *(const float4*)&sA1[k][ty * 8];
            *(float4*)&a1[4] = *(const float4*)&sA1[k][ty * 8 + 4];
            *(float4*)&a2[0] = *(const float4*)&sA2[k][ty * 8];
            *(float4*)&a2[4] = *(const float4*)&sA2[k][ty * 8 + 4];
            *(float4*)&c1[0] = *(const float4*)&sB1[k][tx * 8];
            *(float4*)&c1[4] = *(const float4*)&sB1[k][tx * 8 + 4];
            *(float4*)&c2[0] = *(const float4*)&sB2[k][tx * 8];
            *(float4*)&c2[4] = *(const float4*)&sB2[k][tx * 8 + 4];
            #pragma unroll
            for (int i = 0; i < 8; ++i)
                #pragma unroll
                for (int j = 0; j < 8; ++j) {
                    acc1[i][j] = fmaf(a1[i], c2[j], acc1[i][j]);  // M1: v1_i.v2_j
                    acc2[i][j] = fmaf(a2[i], c1[j], acc2[i][j]);  // M2: v2_i.v1_j
                }
        }
    }
    // epilogue in-place: acc1 <- wn (normal), acc2 <- wm (mirror)
    #pragma unroll
    for (int i = 0; i < 8; ++i)
        #pragma unroll
        for (int j = 0; j < 8; ++j) {
            const float aa = acc1[i][j] - acc2[i][j];   // one f32 sub (M1-M2)
            const float tt = tanh_xla_pos(3.0f * fabsf(aa));
            acc1[i][j] = (aa > 0.0f) ? tt : 0.0f;       // relu(tanh(3a))
            acc2[i][j] = (aa < 0.0f) ? tt : 0.0f;       // relu(tanh(-3a))
        }
    #pragma unroll
    for (int i = 0; i < 8; ++i) {
        const int gi = Ibase + ty * 8 + i;
        float4* p = (float4*)&out[(size_t)gi * NN + Jbase + tx * 8];
        p[0] = make_float4(acc1[i][0], acc1[i][1], acc1[i][2], acc1[i][3]);
        p[1] = make_float4(acc1[i][4], acc1[i][5], acc1[i][6], acc1[i][7]);
    }
    if (bi != bj) {
        #pragma unroll
        for (int j = 0; j < 8; ++j) {
            const int gj = Jbase + tx * 8 + j;
            float4* p = (float4*)&out[(size_t)gj * NN + Ibase + ty * 8];
            p[0] = make_float4(acc2[0][j], acc2[1][j], acc2[2][j], acc2[3][j]);
            p[1] = make_float4(acc2[4][j], acc2[5][j], acc2[6][j], acc2[7][j]);
        }
    }
}

// ---- kernel 3: exact stable top-32 per row, 44-bit radix select ----
// key = (A_bits << 13) | (8191 - col). Uniform early-break when resolved.
__global__ __launch_bounds__(256) void k_topk(float* __restrict__ out)
{
    __shared__ uint32_t hist[4][2048];
    __shared__ uint32_t waveTot[4];
    __shared__ uint32_t bc_bin, bc_ca, bc_m, bc_flag;

    const int row = blockIdx.x;
    const int t = threadIdx.x;
    const int wid = t >> 6, lane = t & 63;
    float* rp = out + (size_t)row * NN;

    float v[32];
    #pragma unroll
    for (int s = 0; s < 8; ++s) {
        const float4 f = *(const float4*)&rp[(s * 256 + t) * 4];
        v[s*4+0] = f.x; v[s*4+1] = f.y; v[s*4+2] = f.z; v[s*4+3] = f.w;
    }
    if (t == 0) bc_flag = 0;

    uint64_t prefix = 0, thr = 0;
    int need = KSEL;
    bool done = false;   // block-uniform at all times

    for (int pass = 0; pass < 4; ++pass) {
        const int shift = 33 - 11 * pass;
        {   // zero hist: 2048 uint4 / 256 thr = 8 each
            const uint4 z = make_uint4(0u, 0u, 0u, 0u);
            uint4* hp = (uint4*)hist;
            #pragma unroll
            for (int i = 0; i < 8; ++i) hp[i * 256 + t] = z;
        }
        __syncthreads();
        #pragma unroll
        for (int s = 0; s < 8; ++s) {
            #pragma unroll
            for (int e = 0; e < 4; ++e) {
                const uint32_t vb = __float_as_uint(v[s*4+e]);
                if (vb == 0u) continue;
                const int gi = s * 1024 + t * 4 + e;
                const uint64_t key = ((uint64_t)vb << 13) | (uint32_t)(8191 - gi);
                if ((key >> (shift + 11)) == prefix)
                    atomicAdd(&hist[wid][(uint32_t)((key >> shift) & 2047u)], 1u);
            }
        }
        __syncthreads();
        uint32_t m[8]; uint32_t tot = 0;
        #pragma unroll
        for (int i = 0; i < 8; ++i) {
            const int b = t * 8 + i;
            m[i] = hist[0][b] + hist[1][b] + hist[2][b] + hist[3][b];
            tot += m[i];
        }
        uint32_t ssum = tot;   // inclusive suffix-sum within wave
        #pragma unroll
        for (int d = 1; d < 64; d <<= 1) {
            const uint32_t o = __shfl_down(ssum, d, 64);
            if (lane + d < 64) ssum += o;
        }
        if (lane == 0) waveTot[wid] = ssum;
        __syncthreads();
        {
            uint32_t above = 0;
            for (int w2 = wid + 1; w2 < 4; ++w2) above += waveTot[w2];
            if (pass == 0) {
                const uint32_t totalAll = waveTot[0] + waveTot[1] + waveTot[2] + waveTot[3];
                if (totalAll < (uint32_t)need && t == 0) bc_flag = 1;  // <32 positives
            }
            uint32_t c = (ssum - tot) + above;       // count in bins above my chunk
            #pragma unroll
            for (int i = 7; i >= 0; --i) {           // walk my 8 bins top-down
                if (c < (uint32_t)need && (uint32_t)need <= c + m[i]) {
                    bc_bin = (uint32_t)(t * 8 + i);  // unique winner
                    bc_ca  = c;
                    bc_m   = m[i];
                }
                c += m[i];
            }
        }
        __syncthreads();
        if (bc_flag) { thr = 1; done = true; }       // keep all positives
        else {
            prefix = (prefix << 11) | (uint64_t)bc_bin;
            need  -= (int)bc_ca;
            if ((uint32_t)need == bc_m) {            // whole bin selected exactly
                thr = prefix << shift;               // bin lower bound
                done = true;
            } else if (pass == 3) { thr = prefix; done = true; }
        }
        if (done) break;                              // block-uniform
        __syncthreads();
    }

    #pragma unroll
    for (int s = 0; s < 8; ++s) {
        float w[4];
        #pragma unroll
        for (int e = 0; e < 4; ++e) {
            const float a = v[s*4+e];
            const uint32_t vb = __float_as_uint(a);
            const int gi = s * 1024 + t * 4 + e;
            const uint64_t key = ((uint64_t)vb << 13) | (uint32_t)(8191 - gi);
            w[e] = (vb != 0u && key >= thr) ? a : 0.f;
        }
        *(float4*)&rp[(s * 256 + t) * 4] = make_float4(w[0], w[1], w[2], w[3]);
    }
}

extern "C" void kernel_launch(void* const* d_in, const int* in_sizes, int n_in,
                              void* d_out, int out_size, void* d_ws, size_t ws_size,
                              hipStream_t stream)
{
    const int*   idx = (const int*)  d_in[0];
    const float* E1  = (const float*)d_in[1];
    const float* E2  = (const float*)d_in[2];
    const float* W1  = (const float*)d_in[3];
    const float* b1  = (const float*)d_in[4];
    const float* W2  = (const float*)d_in[5];
    const float* b2  = (const float*)d_in[6];
    float* out = (float*)d_out;
    float* V1 = (float*)d_ws;                 // 2 MB
    float* V2 = V1 + (size_t)NN * DIM;        // 2 MB

    k_embed<<<NN / 4, 256, 0, stream>>>(idx, E1, E2, W1, b1, W2, b2, V1, V2);
    k_score<<<dim3(NN / TILE, NN / TILE), 256, 0, stream>>>(V1, V2, out);
    k_topk<<<NN, 256, 0, stream>>>(out);
}